// Round 4
// baseline (355.402 us; speedup 1.0000x reference)
//
#include <hip/hip_runtime.h>
#include <cmath>

// Shapes: B=4, V=8, D=64, N=16, H=32, W=32, GROUPS=4
// rotation tables: a = radians(-45*v); c = cos(a), s = sin(a)
#define FSQ 0.70710678118654752440f
__constant__ float CTAB[8] = {1.f,  FSQ, 0.f, -FSQ, -1.f, -FSQ, 0.f, FSQ};
__constant__ float STAB[8] = {0.f, -FSQ, -1.f, -FSQ,  0.f,  FSQ, 1.f, FSQ};

typedef float f4 __attribute__((ext_vector_type(4)));

// ---------------------------------------------------------------------------
// GroupNorm: 16 blocks = (b, group), 1024 threads. Wave-shuffle reduction.
// Writes u_norm into zero-padded (34x34) planes in ws.
// ---------------------------------------------------------------------------
__global__ __launch_bounds__(1024) void gn_kernel(const float* __restrict__ u,
                                                  const float* __restrict__ gw,
                                                  const float* __restrict__ gb,
                                                  float* __restrict__ up)
{
    int blk = blockIdx.x;            // b*4 + g
    int b = blk >> 2, g = blk & 3;
    int t = threadIdx.x;
    const float* src = u + ((size_t)(b * 64 + g * 16) << 10);   // 16384 floats
    float sum = 0.f, sq = 0.f;
    #pragma unroll
    for (int r = 0; r < 16; ++r) {
        float v = src[t + (r << 10)];
        sum += v; sq += v * v;
    }
    // wave-level reduce (64 lanes)
    #pragma unroll
    for (int ofs = 32; ofs > 0; ofs >>= 1) {
        sum += __shfl_down(sum, ofs);
        sq  += __shfl_down(sq, ofs);
    }
    __shared__ float red[16], red2[16];
    int wv = t >> 6;
    if ((t & 63) == 0) { red[wv] = sum; red2[wv] = sq; }
    __syncthreads();
    float s_tot = 0.f, q_tot = 0.f;
    #pragma unroll
    for (int k = 0; k < 16; ++k) { s_tot += red[k]; q_tot += red2[k]; }
    float mu  = s_tot * (1.f / 16384.f);
    float var = q_tot * (1.f / 16384.f) - mu * mu;
    float rs  = rsqrtf(var + 1e-5f);

    float* pb = up + (size_t)(b * 64 + g * 16) * 1156;
    // zero the 132 border cells of each of my 16 padded planes
    for (int k = t; k < 16 * 132; k += 1024) {
        int pl = k / 132, c = k - pl * 132;
        int idx;
        if (c < 34)       idx = c;                       // row 0
        else if (c < 68)  idx = 33 * 34 + (c - 34);      // row 33
        else if (c < 100) idx = (c - 68 + 1) * 34;       // col 0, rows 1..32
        else              idx = (c - 100 + 1) * 34 + 33; // col 33, rows 1..32
        pb[pl * 1156 + idx] = 0.f;
    }
    // normalized data cells: idx = r*1024 + t -> ch = r, pixel = t
    int y = t >> 5, x = t & 31;
    #pragma unroll
    for (int r = 0; r < 16; ++r) {
        float val = (src[t + (r << 10)] - mu) * rs * gw[g * 16 + r] + gb[g * 16 + r];
        pb[r * 1156 + (y + 1) * 34 + (x + 1)] = val;
    }
}

// ---------------------------------------------------------------------------
// 3x3 SAME convs, LDS-staged, 4 OUTPUT CHANNELS PER BLOCK: 768 blocks =
// (b, ogroup, strip). Each block stages the 6-row x 34-col x 64-ci input
// strip (52 KB) into LDS once, then each LDS tap read is FMA'd into 4
// accumulators (one per output channel). ogroups align with weight arrays:
// og 0..15 -> conv_delta, 16..19 -> conv_B, 20..23 -> conv_C.
// ---------------------------------------------------------------------------
__global__ __launch_bounds__(256) void conv_kernel(const float* __restrict__ up,
                                                   const float* __restrict__ wd,
                                                   const float* __restrict__ bd,
                                                   const float* __restrict__ wB,
                                                   const float* __restrict__ wC,
                                                   const float* __restrict__ dtb,
                                                   float* __restrict__ delta,
                                                   float* __restrict__ Bv,
                                                   float* __restrict__ Cv)
{
    __shared__ float sin_[64 * 204];   // 64 ci x 6 rows x 34 cols = 52224 B
    int blk = blockIdx.x;              // b*192 + og*8 + strip
    int strip = blk & 7;
    int og = (blk >> 3) % 24;
    int b = blk / 192;
    int h0 = strip * 4;                // output rows h0..h0+3; padded rows h0..h0+5
    int t = threadIdx.x;

    const float* plane = up + (size_t)b * 73984;   // 64*1156
    for (int idx = t; idx < 13056; idx += 256) {   // 13056 = 64*204 = 256*51
        int ci = idx / 204;
        int rem = idx - ci * 204;
        sin_[idx] = plane[ci * 1156 + h0 * 34 + rem];
    }
    __syncthreads();

    int o0 = og * 4;
    const float* wsel;
    if (o0 < 64)      wsel = wd + (size_t)o0 * 576;
    else if (o0 < 80) wsel = wB + (size_t)(o0 - 64) * 576;
    else              wsel = wC + (size_t)(o0 - 80) * 576;

    int half = t >> 7;                 // ci-half (wave-uniform)
    int px = t & 127;
    int r = px >> 5, c = px & 31;      // output row-in-strip, col
    const float* base = sin_ + r * 34 + c;

    float acc0 = 0.f, acc1 = 0.f, acc2 = 0.f, acc3 = 0.f;
    int ci0 = half * 32;
    for (int ci = ci0; ci < ci0 + 32; ++ci) {
        const float* pp = base + ci * 204;
        const float* wp = wsel + ci * 9;
        #pragma unroll
        for (int dy = 0; dy < 3; ++dy)
            #pragma unroll
            for (int dx = 0; dx < 3; ++dx) {
                float v = pp[dy * 34 + dx];
                int wi = dy * 3 + dx;
                acc0 += v * wp[wi];
                acc1 += v * wp[576 + wi];
                acc2 += v * wp[1152 + wi];
                acc3 += v * wp[1728 + wi];
            }
    }
    __syncthreads();                   // sin_ reuse as reduction scratch
    float4* red4 = (float4*)sin_;
    red4[t] = make_float4(acc0, acc1, acc2, acc3);
    __syncthreads();
    if (t < 128) {
        float4 a = red4[t], bq = red4[t + 128];
        float s0 = a.x + bq.x, s1 = a.y + bq.y, s2 = a.z + bq.z, s3 = a.w + bq.w;
        float s[4] = {s0, s1, s2, s3};
        int pidx = (h0 + r) * 32 + c;  // for t<128: r,c as computed above
        if (o0 < 64) {
            #pragma unroll
            for (int k = 0; k < 4; ++k) {
                float x = s[k] + bd[o0 + k] + dtb[0];
                float sp = (x > 20.f) ? x : log1pf(expf(x));
                sp = fminf(fmaxf(sp, 1e-4f), 5.f);
                delta[((size_t)(b * 64 + o0 + k) << 10) + pidx] = sp;
            }
        } else if (o0 < 80) {
            #pragma unroll
            for (int k = 0; k < 4; ++k)
                Bv[((size_t)(b * 16 + o0 - 64 + k) << 10) + pidx] = s[k];
        } else {
            #pragma unroll
            for (int k = 0; k < 4; ++k)
                Cv[((size_t)(b * 16 + o0 - 80 + k) << 10) + pidx] = s[k];
        }
    }
}

// ---------------------------------------------------------------------------
// Main fused kernel: 8192 blocks = (chunk, b, v, d) with CHUNK IN THE HIGH
// BITS: all 4 n-chunk blocks of one (b,v,d) share blk%8 -> same XCD, so the
// y atomic lines RMW inside a single L2 (no cross-XCD ping-pong) and
// delta/u planes for a given d are L2-resident on one XCD for all 32
// consumer blocks.
// THREAD OWNS 4 CONSECUTIVE PIXELS (p = 4t..4t+3): every delta/u/Bv/Cv load
// and s_out store is one dwordx4 (16 B/lane) -> VMEM ops per thread halved
// vs the scalar-per-pixel layout (round-3 null on occupancy showed the wall
// is the per-wave memory chain, not TLP). s_out stores are nontemporal
// (134 MB streamed, never re-read) to keep s_prev/Bv/Cv/y L2-resident.
// LDS: 4 planes, row stride 35 (odd): bilinear taps <=2-way conflicts for
// all rotations under the 4-px-per-thread mapping.
// Round-1 lesson: no bulk register state held across barriers.
// ---------------------------------------------------------------------------
__global__ __launch_bounds__(256) void fused_state_kernel(
    const float* __restrict__ s_prev, const float* __restrict__ u_t,
    const float* __restrict__ delta, const float* __restrict__ Bv,
    const float* __restrict__ Cv, const float* __restrict__ logA,
    const float* __restrict__ Dp, float* __restrict__ y_out,
    float* __restrict__ s_out)
{
    __shared__ float lds[4 * 1190];   // 19040 B
    __shared__ float Ash[4];
    int blk = blockIdx.x;             // cchunk*2048 + b*512 + v*64 + d
    int cchunk = blk >> 11;
    int rest = blk & 2047;
    int d = rest & 63, v = (rest >> 6) & 7, b = rest >> 9;
    int t = threadIdx.x;

    if (t < 4) Ash[t] = -__expf(logA[d * 16 + cchunk * 4 + t]);
    // zero guard cells (4 planes x 132 border cells; pad col 34 never read)
    for (int k = t; k < 528; k += 256) {
        int pl = k / 132, g = k - pl * 132;
        int idx;
        if (g < 34)       idx = g;                   // row 0
        else if (g < 68)  idx = 33 * 35 + (g - 34);  // row 33
        else if (g < 100) idx = (g - 67) * 35;       // col 0, rows 1..32
        else              idx = (g - 99) * 35 + 33;  // col 33, rows 1..32
        lds[pl * 1190 + idx] = 0.f;
    }

    // 4 planes = 4096 floats per (b,v,d,chunk)
    size_t so = (((size_t)((b * 8 + v) * 64 + d)) << 14) + ((size_t)cchunk << 12);
    const float4* src = (const float4*)(s_prev + so);
    #pragma unroll
    for (int k = 0; k < 4; ++k) {
        int q = t + (k << 8);          // 0..1023 float4s
        float4 val = src[q];
        int lin = q << 2;              // 0..4095
        int nn = lin >> 10, rem = lin & 1023;
        int di = nn * 1190 + ((rem >> 5) + 1) * 35 + (rem & 31) + 1;
        lds[di] = val.x; lds[di + 1] = val.y; lds[di + 2] = val.z; lds[di + 3] = val.w;
    }
    __syncthreads();

    const float cc = CTAB[v], ss = STAB[v];
    const f4* dpl4 = (const f4*)(delta + ((size_t)(b * 64 + d) << 10));
    const f4* upl4 = (const f4*)(u_t   + ((size_t)(b * 64 + d) << 10));
    const f4* bvc4 = (const f4*)(Bv + ((size_t)b << 14) + (cchunk << 12));
    const f4* cvc4 = (const f4*)(Cv + ((size_t)b << 14) + (cchunk << 12));
    f4* soc4   = (f4*)(s_out + so);
    float* yo  = y_out + (((size_t)((b * 8 + v) * 64 + d)) << 10);
    float Dd = Dp[d];

    f4 dd4 = dpl4[t], uv4 = upl4[t];

    // pixel group: p = 4t..4t+3 -> h = t>>3 (uniform), wpx = 4*(t&7)+j
    int h = t >> 3;
    float Yc = (h + 0.5f) * 0.0625f - 1.f;
    float w00[4], w01[4], w10[4], w11[4], duv[4], yacc[4];
    int tb[4];
    #pragma unroll
    for (int j = 0; j < 4; ++j) {
        int wpx = ((t & 7) << 2) | j;
        float X = (wpx + 0.5f) * 0.0625f - 1.f;
        float gx = cc * X - ss * Yc;
        float gy = ss * X + cc * Yc;
        float ix = (gx + 1.f) * 16.f - 0.5f;
        float iy = (gy + 1.f) * 16.f - 0.5f;
        float fx0 = floorf(ix), fy0 = floorf(iy);
        float wx = ix - fx0, wy = iy - fy0;
        int x0 = (int)fx0, y0 = (int)fy0;
        float mx0 = (x0 >= 0 && x0 < 32) ? (1.f - wx) : 0.f;
        float mx1 = (x0 >= -1 && x0 < 31) ? wx : 0.f;
        float my0 = (y0 >= 0 && y0 < 32) ? (1.f - wy) : 0.f;
        float my1 = (y0 >= -1 && y0 < 31) ? wy : 0.f;
        w00[j] = my0 * mx0; w01[j] = my0 * mx1;
        w10[j] = my1 * mx0; w11[j] = my1 * mx1;
        int bx = min(max(x0, -1), 31), by = min(max(y0, -1), 31);
        tb[j] = (by + 1) * 35 + (bx + 1);   // taps: +0,+1,+35,+36 (guard zeroed)
        duv[j] = dd4[j] * uv4[j];
        yacc[j] = 0.f;
    }

    #pragma unroll
    for (int nn = 0; nn < 4; ++nn) {
        f4 B4 = bvc4[(nn << 8) + t];
        f4 C4 = cvc4[(nn << 8) + t];
        f4 sn4;
        #pragma unroll
        for (int j = 0; j < 4; ++j) {
            int si = tb[j] + nn * 1190;
            float bil = lds[si] * w00[j] + lds[si + 1] * w01[j]
                      + lds[si + 35] * w10[j] + lds[si + 36] * w11[j];
            float abar = __expf(dd4[j] * Ash[nn]);
            float sn = abar * bil + duv[j] * B4[j];
            sn4[j] = sn;
            yacc[j] += sn * C4[j];
        }
        __builtin_nontemporal_store(sn4, soc4 + (nn << 8) + t);
    }

    #pragma unroll
    for (int j = 0; j < 4; ++j) {
        float val = yacc[j] + (cchunk == 0 ? uv4[j] * Dd : 0.f);
        atomicAdd(yo + (t << 2) + j, val);
    }
}

// ---------------------------------------------------------------------------
extern "C" void kernel_launch(void* const* d_in, const int* in_sizes, int n_in,
                              void* d_out, int out_size, void* d_ws, size_t ws_size,
                              hipStream_t stream)
{
    const float* u_t    = (const float*)d_in[0];
    const float* s_prev = (const float*)d_in[1];
    const float* gn_w   = (const float*)d_in[2];
    const float* gn_b   = (const float*)d_in[3];
    const float* wd     = (const float*)d_in[4];
    const float* bd     = (const float*)d_in[5];
    const float* wB     = (const float*)d_in[6];
    const float* wC     = (const float*)d_in[7];
    const float* logA   = (const float*)d_in[8];
    const float* Dp     = (const float*)d_in[9];
    const float* dtb    = (const float*)d_in[10];

    float* y_out = (float*)d_out;            // (4,8,64,32,32) = 2097152 floats
    float* s_out = y_out + 2097152;          // (4,8,64,16,32,32) = 33554432 floats

    float* up    = (float*)d_ws;             // padded u_norm: 4*64*1156 = 295936
    float* delta = up + 295936;              // 4*64*1024 = 262144
    float* Bv    = delta + 262144;           // 4*16*1024 = 65536
    float* Cv    = Bv + 65536;               // 65536

    // y is accumulated via atomicAdd from the four n-chunk blocks -> zero first
    hipMemsetAsync(y_out, 0, (size_t)2097152 * sizeof(float), stream);

    hipLaunchKernelGGL(gn_kernel, dim3(16), dim3(1024), 0, stream, u_t, gn_w, gn_b, up);
    hipLaunchKernelGGL(conv_kernel, dim3(768), dim3(256), 0, stream,
                       up, wd, bd, wB, wC, dtb, delta, Bv, Cv);
    hipLaunchKernelGGL(fused_state_kernel, dim3(8192), dim3(256), 0, stream,
                       s_prev, u_t, delta, Bv, Cv, logA, Dp, y_out, s_out);
}

// Round 5
// 306.085 us; speedup vs baseline: 1.1611x; 1.1611x over previous
//
#include <hip/hip_runtime.h>
#include <cmath>

// Shapes: B=4, V=8, D=64, N=16, H=32, W=32, GROUPS=4
// rotation tables: a = radians(-45*v); c = cos(a), s = sin(a)
#define FSQ 0.70710678118654752440f
__constant__ float CTAB[8] = {1.f,  FSQ, 0.f, -FSQ, -1.f, -FSQ, 0.f, FSQ};
__constant__ float STAB[8] = {0.f, -FSQ, -1.f, -FSQ,  0.f,  FSQ, 1.f, FSQ};

typedef float f4 __attribute__((ext_vector_type(4)));

// ---------------------------------------------------------------------------
// GroupNorm: 16 blocks = (b, group), 1024 threads. Wave-shuffle reduction.
// Writes u_norm into zero-padded (34x34) planes in ws.
// ---------------------------------------------------------------------------
__global__ __launch_bounds__(1024) void gn_kernel(const float* __restrict__ u,
                                                  const float* __restrict__ gw,
                                                  const float* __restrict__ gb,
                                                  float* __restrict__ up)
{
    int blk = blockIdx.x;            // b*4 + g
    int b = blk >> 2, g = blk & 3;
    int t = threadIdx.x;
    const float* src = u + ((size_t)(b * 64 + g * 16) << 10);   // 16384 floats
    float sum = 0.f, sq = 0.f;
    #pragma unroll
    for (int r = 0; r < 16; ++r) {
        float v = src[t + (r << 10)];
        sum += v; sq += v * v;
    }
    // wave-level reduce (64 lanes)
    #pragma unroll
    for (int ofs = 32; ofs > 0; ofs >>= 1) {
        sum += __shfl_down(sum, ofs);
        sq  += __shfl_down(sq, ofs);
    }
    __shared__ float red[16], red2[16];
    int wv = t >> 6;
    if ((t & 63) == 0) { red[wv] = sum; red2[wv] = sq; }
    __syncthreads();
    float s_tot = 0.f, q_tot = 0.f;
    #pragma unroll
    for (int k = 0; k < 16; ++k) { s_tot += red[k]; q_tot += red2[k]; }
    float mu  = s_tot * (1.f / 16384.f);
    float var = q_tot * (1.f / 16384.f) - mu * mu;
    float rs  = rsqrtf(var + 1e-5f);

    float* pb = up + (size_t)(b * 64 + g * 16) * 1156;
    // zero the 132 border cells of each of my 16 padded planes
    for (int k = t; k < 16 * 132; k += 1024) {
        int pl = k / 132, c = k - pl * 132;
        int idx;
        if (c < 34)       idx = c;                       // row 0
        else if (c < 68)  idx = 33 * 34 + (c - 34);      // row 33
        else if (c < 100) idx = (c - 68 + 1) * 34;       // col 0, rows 1..32
        else              idx = (c - 100 + 1) * 34 + 33; // col 33, rows 1..32
        pb[pl * 1156 + idx] = 0.f;
    }
    // normalized data cells: idx = r*1024 + t -> ch = r, pixel = t
    int y = t >> 5, x = t & 31;
    #pragma unroll
    for (int r = 0; r < 16; ++r) {
        float val = (src[t + (r << 10)] - mu) * rs * gw[g * 16 + r] + gb[g * 16 + r];
        pb[r * 1156 + (y + 1) * 34 + (x + 1)] = val;
    }
}

// ---------------------------------------------------------------------------
// 3x3 SAME convs, LDS-staged, 4 OUTPUT CHANNELS PER BLOCK: 768 blocks =
// (b, ogroup, strip). Each block stages the 6-row x 34-col x 64-ci input
// strip (52 KB) into LDS once, then each LDS tap read is FMA'd into 4
// accumulators (one per output channel). ogroups align with weight arrays:
// og 0..15 -> conv_delta, 16..19 -> conv_B, 20..23 -> conv_C.
// ---------------------------------------------------------------------------
__global__ __launch_bounds__(256) void conv_kernel(const float* __restrict__ up,
                                                   const float* __restrict__ wd,
                                                   const float* __restrict__ bd,
                                                   const float* __restrict__ wB,
                                                   const float* __restrict__ wC,
                                                   const float* __restrict__ dtb,
                                                   float* __restrict__ delta,
                                                   float* __restrict__ Bv,
                                                   float* __restrict__ Cv)
{
    __shared__ float sin_[64 * 204];   // 64 ci x 6 rows x 34 cols = 52224 B
    int blk = blockIdx.x;              // b*192 + og*8 + strip
    int strip = blk & 7;
    int og = (blk >> 3) % 24;
    int b = blk / 192;
    int h0 = strip * 4;                // output rows h0..h0+3; padded rows h0..h0+5
    int t = threadIdx.x;

    const float* plane = up + (size_t)b * 73984;   // 64*1156
    for (int idx = t; idx < 13056; idx += 256) {   // 13056 = 64*204 = 256*51
        int ci = idx / 204;
        int rem = idx - ci * 204;
        sin_[idx] = plane[ci * 1156 + h0 * 34 + rem];
    }
    __syncthreads();

    int o0 = og * 4;
    const float* wsel;
    if (o0 < 64)      wsel = wd + (size_t)o0 * 576;
    else if (o0 < 80) wsel = wB + (size_t)(o0 - 64) * 576;
    else              wsel = wC + (size_t)(o0 - 80) * 576;

    int half = t >> 7;                 // ci-half (wave-uniform)
    int px = t & 127;
    int r = px >> 5, c = px & 31;      // output row-in-strip, col
    const float* base = sin_ + r * 34 + c;

    float acc0 = 0.f, acc1 = 0.f, acc2 = 0.f, acc3 = 0.f;
    int ci0 = half * 32;
    for (int ci = ci0; ci < ci0 + 32; ++ci) {
        const float* pp = base + ci * 204;
        const float* wp = wsel + ci * 9;
        #pragma unroll
        for (int dy = 0; dy < 3; ++dy)
            #pragma unroll
            for (int dx = 0; dx < 3; ++dx) {
                float v = pp[dy * 34 + dx];
                int wi = dy * 3 + dx;
                acc0 += v * wp[wi];
                acc1 += v * wp[576 + wi];
                acc2 += v * wp[1152 + wi];
                acc3 += v * wp[1728 + wi];
            }
    }
    __syncthreads();                   // sin_ reuse as reduction scratch
    float4* red4 = (float4*)sin_;
    red4[t] = make_float4(acc0, acc1, acc2, acc3);
    __syncthreads();
    if (t < 128) {
        float4 a = red4[t], bq = red4[t + 128];
        float s0 = a.x + bq.x, s1 = a.y + bq.y, s2 = a.z + bq.z, s3 = a.w + bq.w;
        float s[4] = {s0, s1, s2, s3};
        int pidx = (h0 + r) * 32 + c;  // for t<128: r,c as computed above
        if (o0 < 64) {
            #pragma unroll
            for (int k = 0; k < 4; ++k) {
                float x = s[k] + bd[o0 + k] + dtb[0];
                float sp = (x > 20.f) ? x : log1pf(expf(x));
                sp = fminf(fmaxf(sp, 1e-4f), 5.f);
                delta[((size_t)(b * 64 + o0 + k) << 10) + pidx] = sp;
            }
        } else if (o0 < 80) {
            #pragma unroll
            for (int k = 0; k < 4; ++k)
                Bv[((size_t)(b * 16 + o0 - 64 + k) << 10) + pidx] = s[k];
        } else {
            #pragma unroll
            for (int k = 0; k < 4; ++k)
                Cv[((size_t)(b * 16 + o0 - 80 + k) << 10) + pidx] = s[k];
        }
    }
}

// ---------------------------------------------------------------------------
// Main fused kernel: 2048 blocks = (b, v, d); ALL 16 n per block via 4
// sequential phases {stage 4 planes -> sync -> compute -> sync} over ONE
// 19 KB LDS buffer. y accumulates in 4 registers across phases -> single
// dwordx4 store: NO atomics (device-scope atomics bypass the non-coherent
// per-XCD L2s; round-4's stride-4-lane atomics quadrupled y's EA write
// charge to +112 MiB), no memset, no 4x delta/u re-reads.
// Round-1 lesson applied: NO register prefetch of the next chunk, minimal
// cross-phase state (~36 regs: yacc/dd/uv/weights), chunk loop unroll 1 —
// round-1's scratch blowup came from 32 VGPRs of staged data held across
// the phase boundary.
// Thread owns 4 consecutive pixels: delta/u/Bv/Cv loads and s_out/y stores
// are all dwordx4 (16 B/lane). LDS row stride 35 (odd): bilinear taps are
// <=2-way (free) for all 8 rotations under this mapping.
// Plane layout: idx = n*1190 + (y+1)*35 + (x+1); guard border zeroed once,
// staging never dirties it.
// ---------------------------------------------------------------------------
__global__ __launch_bounds__(256) void fused_state_kernel(
    const float* __restrict__ s_prev, const float* __restrict__ u_t,
    const float* __restrict__ delta, const float* __restrict__ Bv,
    const float* __restrict__ Cv, const float* __restrict__ logA,
    const float* __restrict__ Dp, float* __restrict__ y_out,
    float* __restrict__ s_out)
{
    __shared__ float lds[4 * 1190];   // 19040 B
    __shared__ float Ash[16];
    int blk = blockIdx.x;             // b*512 + v*64 + d
    int d = blk & 63, v = (blk >> 6) & 7, b = blk >> 9;
    int t = threadIdx.x;

    if (t < 16) Ash[t] = -__expf(logA[d * 16 + t]);
    // zero guard cells once (4 planes x 132 border cells; pad col 34 never read)
    for (int k = t; k < 528; k += 256) {
        int pl = k / 132, g = k - pl * 132;
        int idx;
        if (g < 34)       idx = g;                   // row 0
        else if (g < 68)  idx = 33 * 35 + (g - 34);  // row 33
        else if (g < 100) idx = (g - 67) * 35;       // col 0, rows 1..32
        else              idx = (g - 99) * 35 + 33;  // col 33, rows 1..32
        lds[pl * 1190 + idx] = 0.f;
    }

    size_t so_base = ((size_t)((b * 8 + v) * 64 + d)) << 14;  // 16384 floats/(b,v,d)
    const float cc = CTAB[v], ss = STAB[v];
    const f4* dpl4 = (const f4*)(delta + ((size_t)(b * 64 + d) << 10));
    const f4* upl4 = (const f4*)(u_t   + ((size_t)(b * 64 + d) << 10));
    float Dd = Dp[d];

    f4 dd4 = dpl4[t], uv4 = upl4[t];

    // pixel group: p = 4t..4t+3 -> h = t>>3 (wave-uniform rows), wpx = 4*(t&7)+j
    int h = t >> 3;
    float Yc = (h + 0.5f) * 0.0625f - 1.f;
    float w00[4], w01[4], w10[4], w11[4], duv[4], yacc[4];
    int tb[4];
    #pragma unroll
    for (int j = 0; j < 4; ++j) {
        int wpx = ((t & 7) << 2) | j;
        float X = (wpx + 0.5f) * 0.0625f - 1.f;
        float gx = cc * X - ss * Yc;
        float gy = ss * X + cc * Yc;
        float ix = (gx + 1.f) * 16.f - 0.5f;
        float iy = (gy + 1.f) * 16.f - 0.5f;
        float fx0 = floorf(ix), fy0 = floorf(iy);
        float wx = ix - fx0, wy = iy - fy0;
        int x0 = (int)fx0, y0 = (int)fy0;
        float mx0 = (x0 >= 0 && x0 < 32) ? (1.f - wx) : 0.f;
        float mx1 = (x0 >= -1 && x0 < 31) ? wx : 0.f;
        float my0 = (y0 >= 0 && y0 < 32) ? (1.f - wy) : 0.f;
        float my1 = (y0 >= -1 && y0 < 31) ? wy : 0.f;
        w00[j] = my0 * mx0; w01[j] = my0 * mx1;
        w10[j] = my1 * mx0; w11[j] = my1 * mx1;
        int bx = min(max(x0, -1), 31), by = min(max(y0, -1), 31);
        tb[j] = (by + 1) * 35 + (bx + 1);   // taps: +0,+1,+35,+36 (guard zeroed)
        duv[j] = dd4[j] * uv4[j];
        yacc[j] = 0.f;
    }

    #pragma unroll 1                   // keep phases compact; no compiler prefetch
    for (int c = 0; c < 4; ++c) {
        if (c) __syncthreads();        // prev phase's LDS reads complete
        // stage 4 planes (4096 floats) direct global->LDS, no held registers
        const float4* src = (const float4*)(s_prev + so_base + ((size_t)c << 12));
        #pragma unroll
        for (int k = 0; k < 4; ++k) {
            int q = t + (k << 8);      // 0..1023 float4s
            float4 val = src[q];
            int lin = q << 2;          // 0..4095
            int nn = lin >> 10, rem = lin & 1023;
            int di = nn * 1190 + ((rem >> 5) + 1) * 35 + (rem & 31) + 1;
            lds[di] = val.x; lds[di + 1] = val.y; lds[di + 2] = val.z; lds[di + 3] = val.w;
        }
        __syncthreads();

        const f4* bvc4 = (const f4*)(Bv + ((size_t)b << 14) + (c << 12));
        const f4* cvc4 = (const f4*)(Cv + ((size_t)b << 14) + (c << 12));
        f4* soc4 = (f4*)(s_out + so_base + ((size_t)c << 12));
        #pragma unroll
        for (int nn = 0; nn < 4; ++nn) {
            f4 B4 = bvc4[(nn << 8) + t];
            f4 C4 = cvc4[(nn << 8) + t];
            float An = Ash[(c << 2) + nn];
            f4 sn4;
            #pragma unroll
            for (int j = 0; j < 4; ++j) {
                int si = tb[j] + nn * 1190;
                float bil = lds[si] * w00[j] + lds[si + 1] * w01[j]
                          + lds[si + 35] * w10[j] + lds[si + 36] * w11[j];
                float abar = __expf(dd4[j] * An);
                float sn = abar * bil + duv[j] * B4[j];
                sn4[j] = sn;
                yacc[j] += sn * C4[j];
            }
            soc4[(nn << 8) + t] = sn4;
        }
    }

    // single vectorized y store — no atomics, no pre-zero
    f4 y4;
    #pragma unroll
    for (int j = 0; j < 4; ++j) y4[j] = yacc[j] + uv4[j] * Dd;
    f4* yo4 = (f4*)(y_out + (((size_t)((b * 8 + v) * 64 + d)) << 10));
    yo4[t] = y4;
}

// ---------------------------------------------------------------------------
extern "C" void kernel_launch(void* const* d_in, const int* in_sizes, int n_in,
                              void* d_out, int out_size, void* d_ws, size_t ws_size,
                              hipStream_t stream)
{
    const float* u_t    = (const float*)d_in[0];
    const float* s_prev = (const float*)d_in[1];
    const float* gn_w   = (const float*)d_in[2];
    const float* gn_b   = (const float*)d_in[3];
    const float* wd     = (const float*)d_in[4];
    const float* bd     = (const float*)d_in[5];
    const float* wB     = (const float*)d_in[6];
    const float* wC     = (const float*)d_in[7];
    const float* logA   = (const float*)d_in[8];
    const float* Dp     = (const float*)d_in[9];
    const float* dtb    = (const float*)d_in[10];

    float* y_out = (float*)d_out;            // (4,8,64,32,32) = 2097152 floats
    float* s_out = y_out + 2097152;          // (4,8,64,16,32,32) = 33554432 floats

    float* up    = (float*)d_ws;             // padded u_norm: 4*64*1156 = 295936
    float* delta = up + 295936;              // 4*64*1024 = 262144
    float* Bv    = delta + 262144;           // 4*16*1024 = 65536
    float* Cv    = Bv + 65536;               // 65536

    hipLaunchKernelGGL(gn_kernel, dim3(16), dim3(1024), 0, stream, u_t, gn_w, gn_b, up);
    hipLaunchKernelGGL(conv_kernel, dim3(768), dim3(256), 0, stream,
                       up, wd, bd, wB, wC, dtb, delta, Bv, Cv);
    hipLaunchKernelGGL(fused_state_kernel, dim3(2048), dim3(256), 0, stream,
                       s_prev, u_t, delta, Bv, Cv, logA, Dp, y_out, s_out);
}

// Round 6
// 300.238 us; speedup vs baseline: 1.1837x; 1.0195x over previous
//
#include <hip/hip_runtime.h>
#include <cmath>

// Shapes: B=4, V=8, D=64, N=16, H=32, W=32, GROUPS=4
// rotation tables: a = radians(-45*v); c = cos(a), s = sin(a)
#define FSQ 0.70710678118654752440f
__constant__ float CTAB[8] = {1.f,  FSQ, 0.f, -FSQ, -1.f, -FSQ, 0.f, FSQ};
__constant__ float STAB[8] = {0.f, -FSQ, -1.f, -FSQ,  0.f,  FSQ, 1.f, FSQ};

typedef float f4 __attribute__((ext_vector_type(4)));

// ---------------------------------------------------------------------------
// GroupNorm: 16 blocks = (b, group), 1024 threads. Wave-shuffle reduction.
// Writes u_norm into zero-padded (34x34) planes in ws.
// ---------------------------------------------------------------------------
__global__ __launch_bounds__(1024) void gn_kernel(const float* __restrict__ u,
                                                  const float* __restrict__ gw,
                                                  const float* __restrict__ gb,
                                                  float* __restrict__ up)
{
    int blk = blockIdx.x;            // b*4 + g
    int b = blk >> 2, g = blk & 3;
    int t = threadIdx.x;
    const float* src = u + ((size_t)(b * 64 + g * 16) << 10);   // 16384 floats
    float sum = 0.f, sq = 0.f;
    #pragma unroll
    for (int r = 0; r < 16; ++r) {
        float v = src[t + (r << 10)];
        sum += v; sq += v * v;
    }
    // wave-level reduce (64 lanes)
    #pragma unroll
    for (int ofs = 32; ofs > 0; ofs >>= 1) {
        sum += __shfl_down(sum, ofs);
        sq  += __shfl_down(sq, ofs);
    }
    __shared__ float red[16], red2[16];
    int wv = t >> 6;
    if ((t & 63) == 0) { red[wv] = sum; red2[wv] = sq; }
    __syncthreads();
    float s_tot = 0.f, q_tot = 0.f;
    #pragma unroll
    for (int k = 0; k < 16; ++k) { s_tot += red[k]; q_tot += red2[k]; }
    float mu  = s_tot * (1.f / 16384.f);
    float var = q_tot * (1.f / 16384.f) - mu * mu;
    float rs  = rsqrtf(var + 1e-5f);

    float* pb = up + (size_t)(b * 64 + g * 16) * 1156;
    // zero the 132 border cells of each of my 16 padded planes
    for (int k = t; k < 16 * 132; k += 1024) {
        int pl = k / 132, c = k - pl * 132;
        int idx;
        if (c < 34)       idx = c;                       // row 0
        else if (c < 68)  idx = 33 * 34 + (c - 34);      // row 33
        else if (c < 100) idx = (c - 68 + 1) * 34;       // col 0, rows 1..32
        else              idx = (c - 100 + 1) * 34 + 33; // col 33, rows 1..32
        pb[pl * 1156 + idx] = 0.f;
    }
    // normalized data cells: idx = r*1024 + t -> ch = r, pixel = t
    int y = t >> 5, x = t & 31;
    #pragma unroll
    for (int r = 0; r < 16; ++r) {
        float val = (src[t + (r << 10)] - mu) * rs * gw[g * 16 + r] + gb[g * 16 + r];
        pb[r * 1156 + (y + 1) * 34 + (x + 1)] = val;
    }
}

// ---------------------------------------------------------------------------
// 3x3 SAME convs, LDS-staged, 4 OUTPUT CHANNELS PER BLOCK: 768 blocks =
// (b, ogroup, strip). Staging is now float4: each ci-row of the 6x34 strip
// is 51 aligned float4s (row start = ci*1156 + h0*34 floats, both 4-mult)
// -> 13 VMEM ops/thread instead of 51 scalar loads.
// ---------------------------------------------------------------------------
__global__ __launch_bounds__(256) void conv_kernel(const float* __restrict__ up,
                                                   const float* __restrict__ wd,
                                                   const float* __restrict__ bd,
                                                   const float* __restrict__ wB,
                                                   const float* __restrict__ wC,
                                                   const float* __restrict__ dtb,
                                                   float* __restrict__ delta,
                                                   float* __restrict__ Bv,
                                                   float* __restrict__ Cv)
{
    __shared__ float sin_[64 * 204];   // 64 ci x 6 rows x 34 cols = 52224 B
    int blk = blockIdx.x;              // b*192 + og*8 + strip
    int strip = blk & 7;
    int og = (blk >> 3) % 24;
    int b = blk / 192;
    int h0 = strip * 4;                // output rows h0..h0+3; padded rows h0..h0+5
    int t = threadIdx.x;

    // float4 staging: 3264 = 64 ci * 51 f4/ci; src f4 index = ci*289 + r4
    const float4* plane4 = (const float4*)(up + (size_t)b * 73984 + h0 * 34);
    float4* s4 = (float4*)sin_;
    #pragma unroll
    for (int k = 0; k < 13; ++k) {
        int i4 = t + (k << 8);
        if (i4 < 3264) {
            int ci = i4 / 51, r4 = i4 - ci * 51;
            s4[i4] = plane4[ci * 289 + r4];
        }
    }
    __syncthreads();

    int o0 = og * 4;
    const float* wsel;
    if (o0 < 64)      wsel = wd + (size_t)o0 * 576;
    else if (o0 < 80) wsel = wB + (size_t)(o0 - 64) * 576;
    else              wsel = wC + (size_t)(o0 - 80) * 576;

    int half = t >> 7;                 // ci-half (wave-uniform)
    int px = t & 127;
    int r = px >> 5, c = px & 31;      // output row-in-strip, col
    const float* base = sin_ + r * 34 + c;

    float acc0 = 0.f, acc1 = 0.f, acc2 = 0.f, acc3 = 0.f;
    int ci0 = half * 32;
    for (int ci = ci0; ci < ci0 + 32; ++ci) {
        const float* pp = base + ci * 204;
        const float* wp = wsel + ci * 9;
        #pragma unroll
        for (int dy = 0; dy < 3; ++dy)
            #pragma unroll
            for (int dx = 0; dx < 3; ++dx) {
                float v = pp[dy * 34 + dx];
                int wi = dy * 3 + dx;
                acc0 += v * wp[wi];
                acc1 += v * wp[576 + wi];
                acc2 += v * wp[1152 + wi];
                acc3 += v * wp[1728 + wi];
            }
    }
    __syncthreads();                   // sin_ reuse as reduction scratch
    float4* red4 = (float4*)sin_;
    red4[t] = make_float4(acc0, acc1, acc2, acc3);
    __syncthreads();
    if (t < 128) {
        float4 a = red4[t], bq = red4[t + 128];
        float s0 = a.x + bq.x, s1 = a.y + bq.y, s2 = a.z + bq.z, s3 = a.w + bq.w;
        float s[4] = {s0, s1, s2, s3};
        int pidx = (h0 + r) * 32 + c;  // for t<128: r,c as computed above
        if (o0 < 64) {
            #pragma unroll
            for (int k = 0; k < 4; ++k) {
                float x = s[k] + bd[o0 + k] + dtb[0];
                float sp = (x > 20.f) ? x : log1pf(expf(x));
                sp = fminf(fmaxf(sp, 1e-4f), 5.f);
                delta[((size_t)(b * 64 + o0 + k) << 10) + pidx] = sp;
            }
        } else if (o0 < 80) {
            #pragma unroll
            for (int k = 0; k < 4; ++k)
                Bv[((size_t)(b * 16 + o0 - 64 + k) << 10) + pidx] = s[k];
        } else {
            #pragma unroll
            for (int k = 0; k < 4; ++k)
                Cv[((size_t)(b * 16 + o0 - 80 + k) << 10) + pidx] = s[k];
        }
    }
}

// ---------------------------------------------------------------------------
// Main fused kernel: 2048 blocks = (b, v, d); 16 n via 4 phases over a
// DOUBLE-BUFFERED LDS (2 x 4 planes x 1190 = 38 KB -> 4 blocks/CU).
// T14 issue-early/write-late: phase c's compute runs while the 4 stage
// loads for phase c+1 are in flight (16 named VGPRs, issued BEFORE compute,
// ds_written to the other buffer AFTER compute). ONE barrier per phase
// (writes go to the buffer nobody reads this phase). This keeps HBM
// requests in flight across the former vmcnt(0) drain points — testing the
// "2.45 TB/s = latency x MLP equilibrium" theory (every prior variant
// drained in-flight ops at 2+ barriers/phase and all sat at 2.45 TB/s).
// Round-1 guards: only 16 held VGPRs, named (no runtime indexing),
// #pragma unroll 1 on the phase loop, asm pin after load issue.
// y accumulates in registers -> single dwordx4 store, no atomics/memset.
// LDS row stride 35 (odd): bilinear taps <=2-way conflicts for all 8
// rotations. Plane layout: idx = n*1190 + (y+1)*35 + (x+1), guard zeroed
// once (both buffers), staging never dirties it.
// ---------------------------------------------------------------------------
__global__ __launch_bounds__(256) void fused_state_kernel(
    const float* __restrict__ s_prev, const float* __restrict__ u_t,
    const float* __restrict__ delta, const float* __restrict__ Bv,
    const float* __restrict__ Cv, const float* __restrict__ logA,
    const float* __restrict__ Dp, float* __restrict__ y_out,
    float* __restrict__ s_out)
{
    __shared__ float lds[2 * 4 * 1190];   // 38080 B
    __shared__ float Ash[16];
    int blk = blockIdx.x;             // b*512 + v*64 + d
    int d = blk & 63, v = (blk >> 6) & 7, b = blk >> 9;
    int t = threadIdx.x;

    if (t < 16) Ash[t] = -__expf(logA[d * 16 + t]);
    // zero guard cells of ALL 8 planes (both buffers) once
    for (int k = t; k < 1056; k += 256) {
        int pl = k / 132, g = k - pl * 132;
        int idx;
        if (g < 34)       idx = g;                   // row 0
        else if (g < 68)  idx = 33 * 35 + (g - 34);  // row 33
        else if (g < 100) idx = (g - 67) * 35;       // col 0, rows 1..32
        else              idx = (g - 99) * 35 + 33;  // col 33, rows 1..32
        lds[pl * 1190 + idx] = 0.f;
    }

    size_t so_base = ((size_t)((b * 8 + v) * 64 + d)) << 14;  // 16384 floats
    const float4* src = (const float4*)(s_prev + so_base);

// scatter one float4 (chunk-local f4 index q) into LDS buffer at base nb
#define DSW(nb, q, val) { int lin = (q) << 2; int nn = lin >> 10; int rem = lin & 1023; \
    int di = (nb) + nn * 1190 + ((rem >> 5) + 1) * 35 + (rem & 31) + 1; \
    lds[di] = (val).x; lds[di + 1] = (val).y; lds[di + 2] = (val).z; lds[di + 3] = (val).w; }

    // prologue: stage chunk 0 into buf0
    {
        float4 a0 = src[t], a1 = src[t + 256], a2 = src[t + 512], a3 = src[t + 768];
        DSW(0, t, a0); DSW(0, t + 256, a1); DSW(0, t + 512, a2); DSW(0, t + 768, a3);
    }

    const float cc = CTAB[v], ss = STAB[v];
    const f4* dpl4 = (const f4*)(delta + ((size_t)(b * 64 + d) << 10));
    const f4* upl4 = (const f4*)(u_t   + ((size_t)(b * 64 + d) << 10));
    float Dd = Dp[d];

    f4 dd4 = dpl4[t], uv4 = upl4[t];

    // pixel group: p = 4t..4t+3 -> h = t>>3 (wave-uniform rows), wpx = 4*(t&7)+j
    int h = t >> 3;
    float Yc = (h + 0.5f) * 0.0625f - 1.f;
    float w00[4], w01[4], w10[4], w11[4], duv[4], yacc[4];
    int tb[4];
    #pragma unroll
    for (int j = 0; j < 4; ++j) {
        int wpx = ((t & 7) << 2) | j;
        float X = (wpx + 0.5f) * 0.0625f - 1.f;
        float gx = cc * X - ss * Yc;
        float gy = ss * X + cc * Yc;
        float ix = (gx + 1.f) * 16.f - 0.5f;
        float iy = (gy + 1.f) * 16.f - 0.5f;
        float fx0 = floorf(ix), fy0 = floorf(iy);
        float wx = ix - fx0, wy = iy - fy0;
        int x0 = (int)fx0, y0 = (int)fy0;
        float mx0 = (x0 >= 0 && x0 < 32) ? (1.f - wx) : 0.f;
        float mx1 = (x0 >= -1 && x0 < 31) ? wx : 0.f;
        float my0 = (y0 >= 0 && y0 < 32) ? (1.f - wy) : 0.f;
        float my1 = (y0 >= -1 && y0 < 31) ? wy : 0.f;
        w00[j] = my0 * mx0; w01[j] = my0 * mx1;
        w10[j] = my1 * mx0; w11[j] = my1 * mx1;
        int bx = min(max(x0, -1), 31), by = min(max(y0, -1), 31);
        tb[j] = (by + 1) * 35 + (bx + 1);   // taps: +0,+1,+35,+36 (guard zeroed)
        duv[j] = dd4[j] * uv4[j];
        yacc[j] = 0.f;
    }
    __syncthreads();                   // buf0 staged + guards zeroed

    #pragma unroll 1                   // do NOT let the compiler hoist all prefetches
    for (int c = 0; c < 4; ++c) {
        int cb = (c & 1) * 4760;       // current buffer base
        // issue next chunk's loads BEFORE compute (in flight under it)
        float4 r0, r1, r2, r3;
        if (c < 3) {
            int o = (c + 1) << 10;
            r0 = src[o + t];       r1 = src[o + t + 256];
            r2 = src[o + t + 512]; r3 = src[o + t + 768];
            asm volatile("" ::: "memory");   // pin issue point
        }

        const f4* bvc4 = (const f4*)(Bv + ((size_t)b << 14) + (c << 12));
        const f4* cvc4 = (const f4*)(Cv + ((size_t)b << 14) + (c << 12));
        f4* soc4 = (f4*)(s_out + so_base + ((size_t)c << 12));
        #pragma unroll
        for (int nn = 0; nn < 4; ++nn) {
            f4 B4 = bvc4[(nn << 8) + t];
            f4 C4 = cvc4[(nn << 8) + t];
            float An = Ash[(c << 2) + nn];
            f4 sn4;
            #pragma unroll
            for (int j = 0; j < 4; ++j) {
                int si = cb + tb[j] + nn * 1190;
                float bil = lds[si] * w00[j] + lds[si + 1] * w01[j]
                          + lds[si + 35] * w10[j] + lds[si + 36] * w11[j];
                float abar = __expf(dd4[j] * An);
                float sn = abar * bil + duv[j] * B4[j];
                sn4[j] = sn;
                yacc[j] += sn * C4[j];
            }
            soc4[(nn << 8) + t] = sn4;
        }

        // write prefetched chunk into the OTHER buffer (nobody reads it now)
        if (c < 3) {
            int nb = cb ^ 4760;
            DSW(nb, t, r0); DSW(nb, t + 256, r1);
            DSW(nb, t + 512, r2); DSW(nb, t + 768, r3);
        }
        __syncthreads();               // single barrier per phase
    }
#undef DSW

    // single vectorized y store — no atomics, no pre-zero
    f4 y4;
    #pragma unroll
    for (int j = 0; j < 4; ++j) y4[j] = yacc[j] + uv4[j] * Dd;
    f4* yo4 = (f4*)(y_out + (((size_t)((b * 8 + v) * 64 + d)) << 10));
    yo4[t] = y4;
}

// ---------------------------------------------------------------------------
extern "C" void kernel_launch(void* const* d_in, const int* in_sizes, int n_in,
                              void* d_out, int out_size, void* d_ws, size_t ws_size,
                              hipStream_t stream)
{
    const float* u_t    = (const float*)d_in[0];
    const float* s_prev = (const float*)d_in[1];
    const float* gn_w   = (const float*)d_in[2];
    const float* gn_b   = (const float*)d_in[3];
    const float* wd     = (const float*)d_in[4];
    const float* bd     = (const float*)d_in[5];
    const float* wB     = (const float*)d_in[6];
    const float* wC     = (const float*)d_in[7];
    const float* logA   = (const float*)d_in[8];
    const float* Dp     = (const float*)d_in[9];
    const float* dtb    = (const float*)d_in[10];

    float* y_out = (float*)d_out;            // (4,8,64,32,32) = 2097152 floats
    float* s_out = y_out + 2097152;          // (4,8,64,16,32,32) = 33554432 floats

    float* up    = (float*)d_ws;             // padded u_norm: 4*64*1156 = 295936
    float* delta = up + 295936;              // 4*64*1024 = 262144
    float* Bv    = delta + 262144;           // 4*16*1024 = 65536
    float* Cv    = Bv + 65536;               // 65536

    hipLaunchKernelGGL(gn_kernel, dim3(16), dim3(1024), 0, stream, u_t, gn_w, gn_b, up);
    hipLaunchKernelGGL(conv_kernel, dim3(768), dim3(256), 0, stream,
                       up, wd, bd, wB, wC, dtb, delta, Bv, Cv);
    hipLaunchKernelGGL(fused_state_kernel, dim3(2048), dim3(256), 0, stream,
                       s_prev, u_t, delta, Bv, Cv, logA, Dp, y_out, s_out);
}